// Round 5
// baseline (212.091 us; speedup 1.0000x reference)
//
#include <hip/hip_runtime.h>
#include <hip/hip_bf16.h>

namespace {

constexpr int Nn = 2048;
constexpr int Hh = 16;
constexpr int Dd = 64;
constexpr int ROWSTR = Hh * Dd;      // 1024 floats between consecutive tokens
constexpr int KVB = 64;              // KV tile rows
constexpr int NTILES = Nn / KVB;     // 32
constexpr int QB = 128;              // q-rows per block (4 stripes x 32)
constexpr int NQT = Nn / QB;         // 16
constexpr int GR = 4;                // KV parity groups; granule = GR*KVB = 256 rows

typedef __bf16 bf16x8 __attribute__((ext_vector_type(8)));
typedef __bf16 bf16x4 __attribute__((ext_vector_type(4)));
typedef float  f32x16 __attribute__((ext_vector_type(16)));

// K tile: row-major [64][64] bf16, 128B rows, 16B-granule XOR swizzle
__device__ __forceinline__ int swzK(int row, int colByte) {
  return (row * 128 + colByte) ^ ((row & 7) << 4);
}
// V^T tile: [d=64][kv=64] bf16, extra bit-3 XOR (b64 reads 2-way = free)
__device__ __forceinline__ int swzV(int row, int colByte) {
  return (row * 128 + colByte) ^ (((row & 7) << 4) | (((row >> 3) & 1) << 3));
}

struct KS { float4 k[4]; };   // 16 VGPR while live
struct VS { float v[16]; };   // 16 VGPR while live

// 1024 threads stage one 4-tile granule (256 KV rows).
__device__ __forceinline__ void issueK(const float* kp, int g0, int tid, KS& s) {
#pragma unroll
  for (int it = 0; it < 4; ++it) {
    int idx = it * 1024 + tid;
    int kvr = idx >> 4, c4 = idx & 15;          // kvr in [0,256)
    s.k[it] = *(const float4*)(kp + (size_t)(g0 + kvr) * ROWSTR + c4 * 4);
  }
}
__device__ __forceinline__ void writeK(char* bufbase, int tid, const KS& s) {
#pragma unroll
  for (int it = 0; it < 4; ++it) {
    int idx = it * 1024 + tid;
    int kvr = idx >> 4, c4 = idx & 15;
    char* kb = bufbase + (kvr >> 6) * 16384;    // tile within granule
    bf16x4 w = { (__bf16)s.k[it].x, (__bf16)s.k[it].y,
                 (__bf16)s.k[it].z, (__bf16)s.k[it].w };
    *(bf16x4*)(kb + swzK(kvr & 63, c4 * 8)) = w;
  }
}
__device__ __forceinline__ void issueV(const float* vp, int g0, int tid, VS& s) {
#pragma unroll
  for (int it = 0; it < 4; ++it) {
    int idx = it * 1024 + tid;
    int d8 = idx & 63, kv4 = idx >> 6;          // kv4 in [0,64)
#pragma unroll
    for (int i2 = 0; i2 < 4; ++i2)
      s.v[it * 4 + i2] = vp[(size_t)(g0 + kv4 * 4 + i2) * ROWSTR + d8];
  }
}
__device__ __forceinline__ void writeV(char* bufbase, int tid, const VS& s) {
#pragma unroll
  for (int it = 0; it < 4; ++it) {
    int idx = it * 1024 + tid;
    int d8 = idx & 63, kv4 = idx >> 6;
    char* vb = bufbase + (kv4 >> 4) * 16384 + 8192;
    bf16x4 w = { (__bf16)s.v[it * 4 + 0], (__bf16)s.v[it * 4 + 1],
                 (__bf16)s.v[it * 4 + 2], (__bf16)s.v[it * 4 + 3] };
    *(bf16x4*)(vb + swzV(d8, (kv4 & 15) * 8)) = w;
  }
}

__global__ __launch_bounds__(1024, 1) void fattn_kernel(
    const float* __restrict__ Qg, const float* __restrict__ Kg,
    const float* __restrict__ Vg, const int* __restrict__ flag,
    float* __restrict__ Og) {
  // 2 granule buffers x 4 tiles x (K 8KB | V^T 8KB) = 128 KB
  __shared__ __align__(16) char smem[2][4][16384];

  const int tid  = threadIdx.x;
  const int lane = tid & 63;
  const int wv   = tid >> 6;    // 0..15
  const int grp  = wv >> 2;     // KV parity group 0..3 (tiles 4i+grp)
  const int wv4  = wv & 3;      // q stripe within the 128-row q-tile
  const int l31  = lane & 31;
  const int g2   = lane >> 5;

  // grid 256, uniform work: block = pair {q-tile 15-j, q-tile j} = 34 KV-tiles.
  // bid&7 -> XCD group of 4 heads for L2 locality.
  const int bid = blockIdx.x;
  const int j   = bid >> 5;                     // 0..7
  const int bh  = ((bid & 7) << 2) | ((bid >> 3) & 3);
  const int b   = bh >> 4;
  const int h   = bh & 15;
  const int causal = flag[0];

  const size_t base = ((size_t)b * Nn * Hh + h) * Dd;
  const float* qp = Qg + base;
  const float* kp = Kg + base;
  const float* vp = Vg + base;
  float*       op = Og + base;

  const float SCALE = 0.125f * 1.44269504088896340736f;  // 1/sqrt(64) * log2(e)

  for (int pass = 0; pass < 2; ++pass) {
    const int Tq = pass ? j : (NQT - 1 - j);
    const int qs = Tq * QB + wv4 * 32;
    // last KV tile this wave needs (inclusive)
    const int TL = causal ? (2 * Tq + (wv4 >> 1)) : (NTILES - 1);
    const int NI = causal ? ((2 * Tq + 5) >> 2) : (NTILES / GR);  // granules staged
    const int nC = (TL >= grp) ? (((TL - grp) >> 2) + 1) : 0;     // computed by this grp

    __syncthreads();   // previous pass's merge reads done before re-staging LDS

    // ---- Q fragments (contiguous k-slot map) ----
    bf16x8 qf[4];
#pragma unroll
    for (int dc = 0; dc < 4; ++dc) {
      const float* qrow = qp + (size_t)(qs + l31) * ROWSTR + dc * 16 + g2 * 8;
      float4 a = *(const float4*)qrow;
      float4 c = *(const float4*)(qrow + 4);
      qf[dc][0] = (__bf16)(a.x * SCALE); qf[dc][1] = (__bf16)(a.y * SCALE);
      qf[dc][2] = (__bf16)(a.z * SCALE); qf[dc][3] = (__bf16)(a.w * SCALE);
      qf[dc][4] = (__bf16)(c.x * SCALE); qf[dc][5] = (__bf16)(c.y * SCALE);
      qf[dc][6] = (__bf16)(c.z * SCALE); qf[dc][7] = (__bf16)(c.w * SCALE);
    }

    f32x16 acc0 = {};   // O cols 0..31 (col = l31)
    f32x16 acc1 = {};   // O cols 32..63
    float m_run = -INFINITY;
    float l_run = 0.0f;

    KS ks; VS vs;

    // ---- prologue: stage granule 0 into buf 0 ----
    issueK(kp, 0, tid, ks);
    writeK(&smem[0][0][0], tid, ks);
    issueV(vp, 0, tid, vs);
    writeV(&smem[0][0][0], tid, vs);

    for (int i = 0; i < NI; ++i) {
      __syncthreads();
      const bool pf = (i + 1 < NI);
      const bool doC = (i < nC);
      const char* kb = &smem[i & 1][grp][0];
      const char* vb = kb + 8192;
      char* nb = &smem[(i + 1) & 1][0][0];

      f32x16 s0, s1;
      bf16x8 pa[4];
      float mnew = m_run, rs = 0.0f, mt = -INFINITY;

      if (doC) {
        // ---- S^T = K . Q^T ----
        s0 = (f32x16){}; s1 = (f32x16){};
#pragma unroll
        for (int dc = 0; dc < 4; ++dc) {
          bf16x8 kf0 = *(const bf16x8*)(kb + swzK(l31,      32 * dc + 16 * g2));
          bf16x8 kf1 = *(const bf16x8*)(kb + swzK(32 + l31, 32 * dc + 16 * g2));
          s0 = __builtin_amdgcn_mfma_f32_32x32x16_bf16(kf0, qf[dc], s0, 0, 0, 0);
          s1 = __builtin_amdgcn_mfma_f32_32x32x16_bf16(kf1, qf[dc], s1, 0, 0, 0);
        }
        // ---- causal mask (this wave's diagonal tile only) ----
        if (causal && (4 * i + grp) == TL) {
          const int kvb = (4 * i + grp) * KVB;
          const int qrow = qs + l31;
#pragma unroll
          for (int rr = 0; rr < 16; ++rr) {
            int rm = (rr & 3) + ((rr >> 2) << 3) + (g2 << 2);
            if (kvb + rm > qrow)      s0[rr] = -INFINITY;
            if (kvb + 32 + rm > qrow) s1[rr] = -INFINITY;
          }
        }
        // ---- max: pairwise tree (depth ~5, not 32-deep chain) ----
        float p8[8];
#pragma unroll
        for (int e = 0; e < 8; ++e)
          p8[e] = fmaxf(fmaxf(s0[e], s0[e + 8]), fmaxf(s1[e], s1[e + 8]));
        mt = fmaxf(fmaxf(fmaxf(p8[0], p8[1]), fmaxf(p8[2], p8[3])),
                   fmaxf(fmaxf(p8[4], p8[5]), fmaxf(p8[6], p8[7])));
        mt = fmaxf(mt, __shfl_xor(mt, 32));
        mnew = fmaxf(m_run, mt);
      }

      // issue next granule's K loads (drain hidden under softmax)
      if (pf) issueK(kp, (i + 1) * GR * KVB, tid, ks);

      if (doC) {
        // ---- exp + sum tree ----
#pragma unroll
        for (int rr = 0; rr < 16; ++rr) {
          s0[rr] = __builtin_amdgcn_exp2f(s0[rr] - mnew);
          s1[rr] = __builtin_amdgcn_exp2f(s1[rr] - mnew);
        }
        float q8[8];
#pragma unroll
        for (int e = 0; e < 8; ++e)
          q8[e] = (s0[e] + s0[e + 8]) + (s1[e] + s1[e + 8]);
        rs = ((q8[0] + q8[1]) + (q8[2] + q8[3])) + ((q8[4] + q8[5]) + (q8[6] + q8[7]));
        rs += __shfl_xor(rs, 32);
        if (__all(mt <= m_run)) {
          l_run += rs;
        } else {
          const float alpha = __builtin_amdgcn_exp2f(m_run - mnew);
#pragma unroll
          for (int rr = 0; rr < 16; ++rr) {
            float at = __shfl(alpha, (rr & 3) + ((rr >> 2) << 3) + (g2 << 2));
            acc0[rr] *= at;
            acc1[rr] *= at;
          }
          l_run = l_run * alpha + rs;
          m_run = mnew;
        }
        // ---- P fragments: pass-through of S^T regs (split-4 k-slot map) ----
#pragma unroll
        for (int kc = 0; kc < 4; ++kc) {
          const f32x16& sv = (kc < 2) ? s0 : s1;
          const int rbase = (kc & 1) * 8;
#pragma unroll
          for (int jj = 0; jj < 8; ++jj) pa[kc][jj] = (__bf16)sv[rbase + jj];
        }
      }

      // write next K (drains K loads), then issue next V (drain under PV)
      if (pf) {
        writeK(nb, tid, ks);
        issueV(vp, (i + 1) * GR * KVB, tid, vs);
      }

      if (doC) {
        // ---- O += P . V ----
#pragma unroll
        for (int kc = 0; kc < 4; ++kc) {
          const int cb = 32 * kc + 8 * g2;
#pragma unroll
          for (int df = 0; df < 2; ++df) {
            const int row = 32 * df + l31;
            bf16x4 v0 = *(const bf16x4*)(vb + swzV(row, cb));
            bf16x4 v1 = *(const bf16x4*)(vb + swzV(row, cb + 16));
            bf16x8 vf = __builtin_shufflevector(v0, v1, 0, 1, 2, 3, 4, 5, 6, 7);
            if (df == 0)
              acc0 = __builtin_amdgcn_mfma_f32_32x32x16_bf16(pa[kc], vf, acc0, 0, 0, 0);
            else
              acc1 = __builtin_amdgcn_mfma_f32_32x32x16_bf16(pa[kc], vf, acc1, 0, 0, 0);
          }
        }
      }

      if (pf) writeV(nb, tid, vs);
    }

    // ---- 4-way merge via LDS (reuses tile memory), group 0 writes out ----
    __syncthreads();
    float* arena = (float*)&smem[0][0][0];   // 12 slots x 2112 floats = 99 KB
    if (grp != 0) {
      float* ab = arena + ((grp - 1) * 4 + wv4) * 2112;
#pragma unroll
      for (int rr = 0; rr < 16; ++rr) {
        int rm = (rr & 3) + ((rr >> 2) << 3) + (g2 << 2);
        ab[rm * 64 + l31]      = acc0[rr];
        ab[rm * 64 + 32 + l31] = acc1[rr];
      }
      if (g2 == 0) { ab[2048 + l31] = m_run; ab[2080 + l31] = l_run; }
    }
    __syncthreads();
    if (grp == 0) {
      const float* a1 = arena + (0 * 4 + wv4) * 2112;
      const float* a2 = arena + (1 * 4 + wv4) * 2112;
      const float* a3 = arena + (2 * 4 + wv4) * 2112;
      const float m1 = a1[2048 + l31], l1 = a1[2080 + l31];
      const float m2 = a2[2048 + l31], l2 = a2[2080 + l31];
      const float m3 = a3[2048 + l31], l3 = a3[2080 + l31];
      const float mN = fmaxf(fmaxf(m_run, m1), fmaxf(m2, m3));
      float f0 = __builtin_amdgcn_exp2f(m_run - mN);
      float f1 = __builtin_amdgcn_exp2f(m1 - mN);
      float f2 = __builtin_amdgcn_exp2f(m2 - mN);
      float f3 = __builtin_amdgcn_exp2f(m3 - mN);
      const float lT = l_run * f0 + l1 * f1 + l2 * f2 + l3 * f3;
      const float linv = 1.0f / lT;
      f0 *= linv; f1 *= linv; f2 *= linv; f3 *= linv;
#pragma unroll
      for (int rr = 0; rr < 16; ++rr) {
        const int rm = (rr & 3) + ((rr >> 2) << 3) + (g2 << 2);
        const float F0 = __shfl(f0, rm);
        const float F1 = __shfl(f1, rm);
        const float F2 = __shfl(f2, rm);
        const float F3 = __shfl(f3, rm);
        const float o0 = acc0[rr] * F0 + a1[rm * 64 + l31] * F1 +
                         a2[rm * 64 + l31] * F2 + a3[rm * 64 + l31] * F3;
        const float o1 = acc1[rr] * F0 + a1[rm * 64 + 32 + l31] * F1 +
                         a2[rm * 64 + 32 + l31] * F2 + a3[rm * 64 + 32 + l31] * F3;
        const size_t row = (size_t)(qs + rm) * ROWSTR;
        op[row + l31]      = o0;
        op[row + 32 + l31] = o1;
      }
    }
  }
}

}  // namespace

extern "C" void kernel_launch(void* const* d_in, const int* in_sizes, int n_in,
                              void* d_out, int out_size, void* d_ws, size_t ws_size,
                              hipStream_t stream) {
  (void)in_sizes; (void)n_in; (void)out_size; (void)d_ws; (void)ws_size;
  const float* q = (const float*)d_in[0];
  const float* k = (const float*)d_in[1];
  const float* v = (const float*)d_in[2];
  const int* flag = (const int*)d_in[3];
  float* out = (float*)d_out;
  fattn_kernel<<<dim3(256), dim3(1024), 0, stream>>>(q, k, v, flag, out);
}

// Round 6
// 72.968 us; speedup vs baseline: 2.9066x; 2.9066x over previous
//
#include <hip/hip_runtime.h>
#include <hip/hip_bf16.h>

namespace {

constexpr int Nn = 2048;
constexpr int Hh = 16;
constexpr int Dd = 64;
constexpr int ROWSTR = Hh * Dd;      // 1024 floats between consecutive tokens
constexpr int KVB = 64;              // KV tile rows
constexpr int NTILES = Nn / KVB;     // 32
constexpr int QB = 128;              // q-rows per block (4 waves x 32)
constexpr int NQT = Nn / QB;         // 16

typedef __bf16 bf16x8 __attribute__((ext_vector_type(8)));
typedef __bf16 bf16x4 __attribute__((ext_vector_type(4)));
typedef float  f32x16 __attribute__((ext_vector_type(16)));

// K tile: row-major [64][64] bf16, 128B rows, 16B-granule XOR swizzle (b128 reads)
__device__ __forceinline__ int swzK(int row, int colByte) {
  return (row * 128 + colByte) ^ ((row & 7) << 4);
}
// V^T tile: [d=64][kv=64] bf16, extra bit-3 XOR (b64 reads 2-way = free)
__device__ __forceinline__ int swzV(int row, int colByte) {
  return (row * 128 + colByte) ^ (((row & 7) << 4) | (((row >> 3) & 1) << 3));
}

struct SR { float4 k[4]; float v[16]; };  // 32 VGPR while live

// 256 threads stage one 64x64 KV tile.
__device__ __forceinline__ void stage_issue(const float* kp, const float* vp,
                                            int kv0, int tid, SR& s) {
#pragma unroll
  for (int it = 0; it < 4; ++it) {
    int idx = it * 256 + tid;
    int kvr = idx >> 4, c4 = idx & 15;
    s.k[it] = *(const float4*)(kp + (size_t)(kv0 + kvr) * ROWSTR + c4 * 4);
  }
#pragma unroll
  for (int it = 0; it < 4; ++it) {
    int idx = it * 256 + tid;
    int d8 = idx & 63, kv4 = idx >> 6;
#pragma unroll
    for (int i2 = 0; i2 < 4; ++i2)
      s.v[it * 4 + i2] = vp[(size_t)(kv0 + kv4 * 4 + i2) * ROWSTR + d8];
  }
}

__device__ __forceinline__ void stage_write(char* kb, char* vb, int tid, const SR& s) {
#pragma unroll
  for (int it = 0; it < 4; ++it) {
    int idx = it * 256 + tid;
    int kvr = idx >> 4, c4 = idx & 15;
    bf16x4 w = { (__bf16)s.k[it].x, (__bf16)s.k[it].y,
                 (__bf16)s.k[it].z, (__bf16)s.k[it].w };
    *(bf16x4*)(kb + swzK(kvr, c4 * 8)) = w;
  }
#pragma unroll
  for (int it = 0; it < 4; ++it) {
    int idx = it * 256 + tid;
    int d8 = idx & 63, kv4 = idx >> 6;
    bf16x4 w = { (__bf16)s.v[it * 4 + 0], (__bf16)s.v[it * 4 + 1],
                 (__bf16)s.v[it * 4 + 2], (__bf16)s.v[it * 4 + 3] };
    *(bf16x4*)(vb + swzV(d8, kv4 * 8)) = w;
  }
}

__global__ __launch_bounds__(256, 2) void fattn_kernel(
    const float* __restrict__ Qg, const float* __restrict__ Kg,
    const float* __restrict__ Vg, const int* __restrict__ flag,
    float* __restrict__ Og) {
  // SINGLE 16KB buffer -> up to ~5 blocks/CU resident (VGPR-bound), LDS allows 10.
  __shared__ __align__(16) char smem[16384];   // K 8KB @0, V^T 8KB @8192

  const int tid  = threadIdx.x;
  const int lane = tid & 63;
  const int wv   = tid >> 6;   // q-stripe 0..3 (32 rows each)
  const int l31  = lane & 31;
  const int g2   = lane >> 5;  // 0/1

  // Heavy/light interleave: even bid = heavy q-tile, odd = light. Adjacent bids
  // share (pairIdx&7) -> same 4-head XCD group for K/V L2 locality.
  const int bid = blockIdx.x;
  const int pidx = bid >> 1;
  const int side = bid & 1;
  const int bh  = ((pidx & 7) << 2) | (pidx >> 6);
  const int ti  = (pidx >> 3) & 7;
  const int b   = bh >> 4;
  const int h   = bh & 15;
  const int causal = flag[0];
  const int Tq  = side ? ti : (NQT - 1 - ti);

  const size_t base = ((size_t)b * Nn * Hh + h) * Dd;
  const float* qp = Qg + base;
  const float* kp = Kg + base;
  const float* vp = Vg + base;
  float*       op = Og + base;

  const float SCALE = 0.125f * 1.44269504088896340736f;  // 1/sqrt(64) * log2(e)

  const int qs = Tq * QB + wv * 32;                    // wave's first q row
  const int Tblock = causal ? (2 * Tq + 2) : NTILES;   // tiles staged by block
  const int Twave  = causal ? ((qs + 31) / KVB + 1) : NTILES;  // computed by wave

  // ---- Q fragments in registers (contiguous k-slot map) ----
  bf16x8 qf[4];
#pragma unroll
  for (int dc = 0; dc < 4; ++dc) {
    const float* qrow = qp + (size_t)(qs + l31) * ROWSTR + dc * 16 + g2 * 8;
    float4 a = *(const float4*)qrow;
    float4 c = *(const float4*)(qrow + 4);
    qf[dc][0] = (__bf16)(a.x * SCALE); qf[dc][1] = (__bf16)(a.y * SCALE);
    qf[dc][2] = (__bf16)(a.z * SCALE); qf[dc][3] = (__bf16)(a.w * SCALE);
    qf[dc][4] = (__bf16)(c.x * SCALE); qf[dc][5] = (__bf16)(c.y * SCALE);
    qf[dc][6] = (__bf16)(c.z * SCALE); qf[dc][7] = (__bf16)(c.w * SCALE);
  }

  f32x16 acc0 = {};   // O cols 0..31  (col = l31)
  f32x16 acc1 = {};   // O cols 32..63
  float m_run = -INFINITY;
  float l_run = 0.0f;

  SR st;

  // ---- prologue: stage tile 0 ----
  stage_issue(kp, vp, 0, tid, st);
  stage_write(smem, smem + 8192, tid, st);

  for (int t = 0; t < Tblock; ++t) {
    __syncthreads();                       // A: tile t's writes visible
    const bool pf = (t + 1 < Tblock);
    // T14: issue next tile's loads now; drain hides under compute(t)
    if (pf) stage_issue(kp, vp, (t + 1) * KVB, tid, st);

    if (t < Twave) {
      const char* kb = smem;
      const char* vb = smem + 8192;

      // ---- S^T = K . Q^T   (swapped: rows = kv, cols = q) ----
      f32x16 s0 = {}, s1 = {};
#pragma unroll
      for (int dc = 0; dc < 4; ++dc) {
        bf16x8 kf0 = *(const bf16x8*)(kb + swzK(l31,      32 * dc + 16 * g2));
        bf16x8 kf1 = *(const bf16x8*)(kb + swzK(32 + l31, 32 * dc + 16 * g2));
        s0 = __builtin_amdgcn_mfma_f32_32x32x16_bf16(kf0, qf[dc], s0, 0, 0, 0);
        s1 = __builtin_amdgcn_mfma_f32_32x32x16_bf16(kf1, qf[dc], s1, 0, 0, 0);
      }

      // ---- causal mask (wave's diagonal tile only) ----
      if (causal && t == Twave - 1) {
        const int kvb = t * KVB;
        const int qrow = qs + l31;
#pragma unroll
        for (int rr = 0; rr < 16; ++rr) {
          int rm = (rr & 3) + ((rr >> 2) << 3) + (g2 << 2);
          if (kvb + rm > qrow)      s0[rr] = -INFINITY;
          if (kvb + 32 + rm > qrow) s1[rr] = -INFINITY;
        }
      }

      // ---- max: pairwise tree (depth ~6, not 32-chain) ----
      float p8[8];
#pragma unroll
      for (int e = 0; e < 8; ++e)
        p8[e] = fmaxf(fmaxf(s0[e], s0[e + 8]), fmaxf(s1[e], s1[e + 8]));
      float mt = fmaxf(fmaxf(fmaxf(p8[0], p8[1]), fmaxf(p8[2], p8[3])),
                       fmaxf(fmaxf(p8[4], p8[5]), fmaxf(p8[6], p8[7])));
      mt = fmaxf(mt, __shfl_xor(mt, 32));
      const float mnew = fmaxf(m_run, mt);

      // ---- exp + sum tree ----
#pragma unroll
      for (int rr = 0; rr < 16; ++rr) {
        s0[rr] = __builtin_amdgcn_exp2f(s0[rr] - mnew);
        s1[rr] = __builtin_amdgcn_exp2f(s1[rr] - mnew);
      }
      float q8[8];
#pragma unroll
      for (int e = 0; e < 8; ++e)
        q8[e] = (s0[e] + s0[e + 8]) + (s1[e] + s1[e + 8]);
      float rs = ((q8[0] + q8[1]) + (q8[2] + q8[3])) +
                 ((q8[4] + q8[5]) + (q8[6] + q8[7]));
      rs += __shfl_xor(rs, 32);
      if (__all(mt <= m_run)) {          // no row max changed: skip rescale
        l_run += rs;
      } else {
        const float alpha = __builtin_amdgcn_exp2f(m_run - mnew);
#pragma unroll
        for (int rr = 0; rr < 16; ++rr) {
          float at = __shfl(alpha, (rr & 3) + ((rr >> 2) << 3) + (g2 << 2));
          acc0[rr] *= at;
          acc1[rr] *= at;
        }
        l_run = l_run * alpha + rs;
        m_run = mnew;
      }

      // ---- P fragments: pass-through of S^T regs (split-4 k-slot map) ----
      bf16x8 pa[4];
#pragma unroll
      for (int kc = 0; kc < 4; ++kc) {
        const f32x16& sv = (kc < 2) ? s0 : s1;
        const int rbase = (kc & 1) * 8;
#pragma unroll
        for (int jj = 0; jj < 8; ++jj) pa[kc][jj] = (__bf16)sv[rbase + jj];
      }

      // ---- O += P . V  (V read d-major from V^T) ----
#pragma unroll
      for (int kc = 0; kc < 4; ++kc) {
        const int cb = 32 * kc + 8 * g2;
#pragma unroll
        for (int df = 0; df < 2; ++df) {
          const int row = 32 * df + l31;
          bf16x4 v0 = *(const bf16x4*)(vb + swzV(row, cb));
          bf16x4 v1 = *(const bf16x4*)(vb + swzV(row, cb + 16));
          bf16x8 vf = __builtin_shufflevector(v0, v1, 0, 1, 2, 3, 4, 5, 6, 7);
          if (df == 0)
            acc0 = __builtin_amdgcn_mfma_f32_32x32x16_bf16(pa[kc], vf, acc0, 0, 0, 0);
          else
            acc1 = __builtin_amdgcn_mfma_f32_32x32x16_bf16(pa[kc], vf, acc1, 0, 0, 0);
        }
      }
    }

    __syncthreads();                       // B: tile t's reads done
    if (pf) stage_write(smem, smem + 8192, tid, st);
  }

  // ---- epilogue: O = acc / l ----
  const float linv = 1.0f / l_run;
#pragma unroll
  for (int rr = 0; rr < 16; ++rr) {
    const int rm = (rr & 3) + ((rr >> 2) << 3) + (g2 << 2);
    const float li = __shfl(linv, rm);
    const size_t row = (size_t)(qs + rm) * ROWSTR;
    op[row + l31]      = acc0[rr] * li;
    op[row + 32 + l31] = acc1[rr] * li;
  }
}

}  // namespace

extern "C" void kernel_launch(void* const* d_in, const int* in_sizes, int n_in,
                              void* d_out, int out_size, void* d_ws, size_t ws_size,
                              hipStream_t stream) {
  (void)in_sizes; (void)n_in; (void)out_size; (void)d_ws; (void)ws_size;
  const float* q = (const float*)d_in[0];
  const float* k = (const float*)d_in[1];
  const float* v = (const float*)d_in[2];
  const int* flag = (const int*)d_in[3];
  float* out = (float*)d_out;
  fattn_kernel<<<dim3(512), dim3(256), 0, stream>>>(q, k, v, flag, out);
}